// Round 5
// baseline (757.308 us; speedup 1.0000x reference)
//
#include <hip/hip_runtime.h>

// Problem constants (match reference setup_inputs)
#define NN 50000
#define EE 800000
#define DD 256
#define LL 3
#define GG 512
#define MPAD 50048  // 782 * 64, GEMM row-tile padding

typedef __attribute__((ext_vector_type(4))) _Float16 half4;
typedef __attribute__((ext_vector_type(8))) _Float16 half8;
typedef __attribute__((ext_vector_type(16))) float floatx16;

// ---------------------------------------------------------------------------
// fp32 -> fp16 convert of x (one-time; h lives in fp16 planes from then on).
// ---------------------------------------------------------------------------
__global__ void k_convert(const float* __restrict__ x, _Float16* __restrict__ h16) {
    int i = blockIdx.x * 256 + threadIdx.x;  // float4 groups
    if (i >= NN * DD / 4) return;
    float4 v = ((const float4*)x)[i];
    half4 o;
    o.x = (_Float16)v.x; o.y = (_Float16)v.y; o.z = (_Float16)v.z; o.w = (_Float16)v.w;
    ((half4*)h16)[i] = o;
}

// ---------------------------------------------------------------------------
// CSR build: histogram -> 2-kernel scan (scan2 folded into scan3) -> scatter
// ---------------------------------------------------------------------------
__global__ void k_hist(const int* __restrict__ dst, int* __restrict__ deg, int e) {
    int i = blockIdx.x * blockDim.x + threadIdx.x;
    if (i < e) atomicAdd(&deg[dst[i]], 1);
}

__global__ void k_scan1(const int* __restrict__ deg, int* __restrict__ rp,
                        int* __restrict__ bsum, int n) {
    __shared__ int s[1024];
    int t = threadIdx.x;
    int i = blockIdx.x * 1024 + t;
    int v = (i < n) ? deg[i] : 0;
    s[t] = v;
    __syncthreads();
    for (int off = 1; off < 1024; off <<= 1) {
        int tmp = (t >= off) ? s[t - off] : 0;
        __syncthreads();
        s[t] += tmp;
        __syncthreads();
    }
    if (i < n) rp[i] = s[t] - v;          // local exclusive
    if (t == 1023) bsum[blockIdx.x] = s[1023];
}

// Adds block offsets (each block redundantly scans the <=64 block sums in one
// wave — cheaper than a separate kernel + serialization). Writes row_ptr[N].
__global__ void k_scan3(int* __restrict__ rp, const int* __restrict__ bsum,
                        int* __restrict__ cursor, int n, int nb,
                        int* __restrict__ total_out) {
    __shared__ int s_off, s_tot;
    if (threadIdx.x < 64) {
        int lane = threadIdx.x;
        int v = (lane < nb) ? bsum[lane] : 0;
        int incl = v;
        for (int off = 1; off < 64; off <<= 1) {
            int u = __shfl_up(incl, off);
            if (lane >= off) incl += u;
        }
        if (lane == (int)blockIdx.x) s_off = incl - v;
        if (lane == 63) s_tot = incl;
    }
    __syncthreads();
    int i = blockIdx.x * 1024 + threadIdx.x;
    if (i < n) {
        int v = rp[i] + s_off;
        rp[i] = v;
        cursor[i] = v;
    }
    if (blockIdx.x == 0 && threadIdx.x == 0) *total_out = s_tot;
}

__global__ void k_scatter(const int* __restrict__ src, const int* __restrict__ dst,
                          int* __restrict__ cursor, int* __restrict__ csr_src, int e) {
    int i = blockIdx.x * blockDim.x + threadIdx.x;
    if (i < e) {
        int d = dst[i];
        int pos = atomicAdd(&cursor[d], 1);
        csr_src[pos] = src[i];
    }
}

// ---------------------------------------------------------------------------
// Pre-pack W (fp32 [256,256], k-major) into fp16 MFMA B-fragments for
// mfma_f32_32x32x16_f16. Fragment (ks,nt): lane l holds
// B[ks*16 + (l>>5)*8 + j][nt*32 + (l&31)], j=0..7, 16B contiguous per lane.
// ---------------------------------------------------------------------------
__global__ void k_wpack(const float* __restrict__ Ws1, const float* __restrict__ Ws2,
                        _Float16* __restrict__ Wp) {
    int tid  = blockIdx.x * 256 + threadIdx.x;  // 6*16*8*64 = 49152
    int lane = tid & 63;
    int nt   = (tid >> 6) & 7;
    int ks   = (tid >> 9) & 15;
    int w    = tid >> 13;
    if (w >= 6) return;
    int l = w >> 1, s = w & 1;
    const float* W = (s == 0 ? Ws1 : Ws2) + (size_t)l * DD * DD;
    int kbase = ks * 16 + (lane >> 5) * 8;
    int n     = nt * 32 + (lane & 31);
    half8 hi;
#pragma unroll
    for (int j = 0; j < 8; ++j) hi[j] = (_Float16)W[(size_t)(kbase + j) * DD + n];
    ((half8*)Wp)[(((size_t)w * 16 + ks) * 8 + nt) * 64 + lane] = hi;
}

// ---------------------------------------------------------------------------
// Fused GIN layer: agg = h + sum_neighbors h  (gather into LDS), then
// h_out = relu(relu(agg@W1+b1)@W2+b2) via two MFMA GEMMs.
// Block: 256 threads = 4 waves, one 64-row x 256-col tile.
// Gather phase: wave w aggregates nodes w*16..w*16+15 (lane-parallel edge
// list prefetch, shfl broadcast, 4-deep unrolled row loads, packed fp16
// accumulate) writing the agg tile to LDS in the XOR-swizzled layout that
// GEMM1's ds_read_b128 A-fragment reads expect (conflict-free).
// The same 32 KB LDS tile is reused for t between GEMM1 and GEMM2.
// ---------------------------------------------------------------------------
__global__ __launch_bounds__(256) void k_gmlp(
        const _Float16* __restrict__ Hin,  // prev plane [MPAD, 256]
        const int* __restrict__ row_ptr, const int* __restrict__ csr_src,
        const _Float16* __restrict__ Wp1, const float* __restrict__ b1,
        const _Float16* __restrict__ Wp2, const float* __restrict__ b2,
        _Float16* __restrict__ Hout,       // next plane [MPAD, 256]
        float* __restrict__ Fout) {        // node_embed + l*256, row stride 768
    __shared__ _Float16 tile[64 * 256];    // 32 KB: agg, then t
    int t    = threadIdx.x;
    int lane = t & 63;
    int w    = t >> 6;
    int wm   = w >> 1, wn = w & 1;
    int r0   = blockIdx.x * 64;

    // ---- gather phase: 16 nodes per wave ----
    {
        int n0 = r0 + w * 16;
        int rpi = n0 + (lane < 16 ? lane : 16);
        int rpv = row_ptr[rpi < NN ? rpi : NN];
        for (int i = 0; i < 16; ++i) {
            int n  = n0 + i;
            int lr = w * 16 + i;
            half4 acc; acc.x = acc.y = acc.z = acc.w = (_Float16)0;
            if (n < NN) {
                int beg = __shfl(rpv, i), end = __shfl(rpv, i + 1);
                int deg = end - beg;
                acc = ((const half4*)(Hin + (size_t)n * DD))[lane];
                int idx = (lane < deg) ? csr_src[beg + lane] : 0;
                int d64 = deg < 64 ? deg : 64;
                int j = 0;
                for (; j + 4 <= d64; j += 4) {
                    int s0 = __shfl(idx, j + 0);
                    int s1 = __shfl(idx, j + 1);
                    int s2 = __shfl(idx, j + 2);
                    int s3 = __shfl(idx, j + 3);
                    half4 v0 = ((const half4*)(Hin + (size_t)s0 * DD))[lane];
                    half4 v1 = ((const half4*)(Hin + (size_t)s1 * DD))[lane];
                    half4 v2 = ((const half4*)(Hin + (size_t)s2 * DD))[lane];
                    half4 v3 = ((const half4*)(Hin + (size_t)s3 * DD))[lane];
                    acc += v0; acc += v1; acc += v2; acc += v3;
                }
                for (; j < d64; ++j) {
                    int s = __shfl(idx, j);
                    acc += ((const half4*)(Hin + (size_t)s * DD))[lane];
                }
                for (int e = beg + 64; e < end; ++e) {  // rare high-degree tail
                    int s = csr_src[e];
                    acc += ((const half4*)(Hin + (size_t)s * DD))[lane];
                }
            }
            // swizzled LDS store: col c = lane*4 halfs; 16B-block idx ^= lr&7
            int blk = lane >> 1;
            *(half4*)&tile[lr * 256 + (((blk ^ (lr & 7)) << 3) | ((lane & 1) << 2))] = acc;
        }
    }
    __syncthreads();

    // ---- GEMM1: acc = agg @ W1 (A fragments from swizzled LDS) ----
    const half8* B1 = (const half8*)Wp1;
    int r = wm * 32 + (lane & 31);  // local A row for this lane

    floatx16 acc[4];
#pragma unroll
    for (int nt = 0; nt < 4; ++nt)
#pragma unroll
        for (int i = 0; i < 16; ++i) acc[nt][i] = 0.0f;

#pragma unroll 4
    for (int ks = 0; ks < 16; ++ks) {
        int kblk = ks * 2 + (lane >> 5);
        half8 a = *(const half8*)&tile[r * 256 + ((kblk ^ (r & 7)) << 3)];
#pragma unroll
        for (int nt = 0; nt < 4; ++nt) {
            half8 b = B1[(size_t)(ks * 8 + wn * 4 + nt) * 64 + lane];
            acc[nt] = __builtin_amdgcn_mfma_f32_32x32x16_f16(a, b, acc[nt], 0, 0, 0);
        }
    }
    __syncthreads();  // all GEMM1 reads done before tile is overwritten with t

    // ---- epilogue 1: t = relu(acc + b1) -> LDS (fp16, swizzled) ----
#pragma unroll
    for (int nt = 0; nt < 4; ++nt) {
        int c  = wn * 128 + nt * 32 + (lane & 31);
        float bv = b1[c];
#pragma unroll
        for (int reg = 0; reg < 16; ++reg) {
            int lr = wm * 32 + (reg & 3) + 8 * (reg >> 2) + 4 * (lane >> 5);
            float v = fmaxf(acc[nt][reg] + bv, 0.0f);
            tile[lr * 256 + ((((c >> 3) ^ (lr & 7)) << 3) | (c & 7))] = (_Float16)v;
        }
    }
    __syncthreads();

    // ---- GEMM2: acc2 = t @ W2 ----
    const half8* B2 = (const half8*)Wp2;
    floatx16 acc2[4];
#pragma unroll
    for (int nt = 0; nt < 4; ++nt)
#pragma unroll
        for (int i = 0; i < 16; ++i) acc2[nt][i] = 0.0f;

#pragma unroll 4
    for (int ks = 0; ks < 16; ++ks) {
        int kblk = ks * 2 + (lane >> 5);
        half8 a = *(const half8*)&tile[r * 256 + ((kblk ^ (r & 7)) << 3)];
#pragma unroll
        for (int nt = 0; nt < 4; ++nt) {
            half8 b = B2[(size_t)(ks * 8 + wn * 4 + nt) * 64 + lane];
            acc2[nt] = __builtin_amdgcn_mfma_f32_32x32x16_f16(a, b, acc2[nt], 0, 0, 0);
        }
    }

    // ---- epilogue 2: h = relu(acc2 + b2) -> fp16 plane + fp32 node_embed ----
#pragma unroll
    for (int nt = 0; nt < 4; ++nt) {
        int col = wn * 128 + nt * 32 + (lane & 31);
        float bv = b2[col];
#pragma unroll
        for (int reg = 0; reg < 16; ++reg) {
            int row = r0 + wm * 32 + (reg & 3) + 8 * (reg >> 2) + 4 * (lane >> 5);
            if (row < NN) {
                float v = fmaxf(acc2[nt][reg] + bv, 0.0f);
                Hout[(size_t)row * DD + col] = (_Float16)v;
                Fout[(size_t)row * 768 + col] = v;
            }
        }
    }
}

// ---------------------------------------------------------------------------
// Mean-pool per graph from the three fp16 h planes (half the bytes of the
// fp32 node_embed). 192 threads: plane p = t>>6, lane q covers half4 cols.
// ---------------------------------------------------------------------------
__global__ void k_pool(const _Float16* __restrict__ h1,
                       const _Float16* __restrict__ h2,
                       const _Float16* __restrict__ h3,
                       const int* __restrict__ batch,
                       float* __restrict__ graph_embed) {
    int g = blockIdx.x;
    int t = threadIdx.x;  // 0..191
    int p = t >> 6, q = t & 63;
    const _Float16* hp = (p == 0) ? h1 : (p == 1) ? h2 : h3;
    int start, end;
    { int l = 0, h = NN; while (l < h) { int m = (l + h) >> 1; if (batch[m] < g) l = m + 1; else h = m; } start = l; }
    { int l = 0, h = NN; while (l < h) { int m = (l + h) >> 1; if (batch[m] < g + 1) l = m + 1; else h = m; } end = l; }
    float ax = 0.f, ay = 0.f, az = 0.f, aw = 0.f;
    for (int n = start; n < end; ++n) {
        half4 v = ((const half4*)(hp + (size_t)n * DD))[q];
        ax += (float)v.x; ay += (float)v.y; az += (float)v.z; aw += (float)v.w;
    }
    int cnt = end - start;
    float inv = 1.0f / (float)(cnt > 0 ? cnt : 1);
    float4 o; o.x = ax * inv; o.y = ay * inv; o.z = az * inv; o.w = aw * inv;
    ((float4*)(graph_embed + (size_t)g * 768 + p * 256))[q] = o;
}

// ---------------------------------------------------------------------------
extern "C" void kernel_launch(void* const* d_in, const int* in_sizes, int n_in,
                              void* d_out, int out_size, void* d_ws, size_t ws_size,
                              hipStream_t stream) {
    const float* x     = (const float*)d_in[0];  // [N, 256]
    const int*   ei    = (const int*)d_in[1];    // [2, E]
    const int*   batch = (const int*)d_in[2];    // [N] (sorted)
    const float* Ws1   = (const float*)d_in[3];  // [L, 256, 256]
    const float* bs1   = (const float*)d_in[4];  // [L, 256]
    const float* Ws2   = (const float*)d_in[5];  // [L, 256, 256]
    const float* bs2   = (const float*)d_in[6];  // [L, 256]

    float* out         = (float*)d_out;
    float* graph_embed = out;                     // [G, 768]
    float* node_embed  = out + (size_t)GG * 768;  // [N, 768]

    // Workspace (re-poisoned before every call; fully rebuilt here)
    const size_t plane = (size_t)MPAD * DD;
    _Float16* h16 = (_Float16*)d_ws;                 // 4 planes [MPAD, 256]
    _Float16* Wp  = h16 + 4 * plane;                 // 6 * 65536 halfs
    int* csr_src = (int*)(Wp + (size_t)6 * 65536);   // [E]
    int* row_ptr = csr_src + EE;                     // [N+1]
    int* cursor  = row_ptr + (NN + 1);               // [N] (also deg)
    int* bsum    = cursor + NN;                      // [64]

    const int* src = ei;       // edge_index[0]
    const int* dst = ei + EE;  // edge_index[1]

    const int NB = (NN + 1023) / 1024;  // 49 scan blocks

    // x -> fp16 plane 0, pack weights
    k_convert<<<(NN * DD / 4 + 255) / 256, 256, 0, stream>>>(x, h16);
    k_wpack<<<192, 256, 0, stream>>>(Ws1, Ws2, Wp);

    // Build CSR (dst -> list of src)
    hipMemsetAsync(cursor, 0, NN * sizeof(int), stream);
    k_hist<<<(EE + 255) / 256, 256, 0, stream>>>(dst, cursor, EE);
    k_scan1<<<NB, 1024, 0, stream>>>(cursor, row_ptr, bsum, NN);
    k_scan3<<<NB, 1024, 0, stream>>>(row_ptr, bsum, cursor, NN, NB, row_ptr + NN);
    k_scatter<<<(EE + 255) / 256, 256, 0, stream>>>(src, dst, cursor, csr_src, EE);

    for (int l = 0; l < LL; ++l) {
        // fused: agg (gather) + h = relu(relu(agg@W1+b1)@W2+b2)
        k_gmlp<<<MPAD / 64, 256, 0, stream>>>(
            h16 + (size_t)l * plane, row_ptr, csr_src,
            Wp + (size_t)(2 * l + 0) * 65536, bs1 + (size_t)l * DD,
            Wp + (size_t)(2 * l + 1) * 65536, bs2 + (size_t)l * DD,
            h16 + (size_t)(l + 1) * plane, node_embed + (size_t)l * DD);
    }

    k_pool<<<GG, 192, 0, stream>>>(h16 + plane, h16 + 2 * plane, h16 + 3 * plane,
                                   batch, graph_embed);
}